// Round 7
// baseline (504.707 us; speedup 1.0000x reference)
//
#include <hip/hip_runtime.h>

#define N_NODES 100000
#define N_EDGES 600000
#define DIM 128
#define SCAN_B 1024
#define NCHUNK 98    // ceil(100000/1024)
#define GEMM_BLOCKS 1564   // 782 row-blocks x 2 col-groups
#define AGG_BLOCKS 6250

typedef __attribute__((ext_vector_type(4))) float f32x4;
typedef __attribute__((ext_vector_type(8))) short bf16x8;
typedef __attribute__((ext_vector_type(4))) unsigned short u16x4;
typedef __attribute__((ext_vector_type(8))) unsigned short u16x8;

__device__ __forceinline__ unsigned short f2bf(float f) {
    union { float f; unsigned u; } cv; cv.f = f;
    unsigned r = (cv.u + 0x7FFFu + ((cv.u >> 16) & 1u)) >> 16;
    return (unsigned short)r;
}
__device__ __forceinline__ float bf2f(unsigned short v) {
    union { unsigned u; float f; } c; c.u = ((unsigned)v) << 16; return c.f;
}

// ---------------- setup: degree / scan / csr fill / weight pack ----------------

__global__ void k_degree(const int* __restrict__ src, int* __restrict__ degi) {
    int e = blockIdx.x * 256 + threadIdx.x;
    if (e < N_EDGES) atomicAdd(&degi[src[e]], 1);
}

__global__ void k_chunksum(const int* __restrict__ degi, int* __restrict__ bsum) {
    __shared__ int sm[SCAN_B];
    int i = blockIdx.x * SCAN_B + threadIdx.x;
    sm[threadIdx.x] = (i < N_NODES) ? degi[i] : 0;
    __syncthreads();
    for (int s = SCAN_B / 2; s > 0; s >>= 1) {
        if (threadIdx.x < (unsigned)s) sm[threadIdx.x] += sm[threadIdx.x + s];
        __syncthreads();
    }
    if (threadIdx.x == 0) bsum[blockIdx.x] = sm[0];
}

__global__ void k_scanb(int* __restrict__ bsum, int nb) {
    __shared__ int sm[128];
    int t = threadIdx.x;
    int v = (t < nb) ? bsum[t] : 0;
    sm[t] = v; __syncthreads();
    for (int s = 1; s < 128; s <<= 1) {
        int a = (t >= s) ? sm[t - s] : 0;
        __syncthreads();
        sm[t] += a;
        __syncthreads();
    }
    if (t < nb) bsum[t] = sm[t] - v;  // exclusive
}

__global__ void k_rowptr(const int* __restrict__ degi, const int* __restrict__ bsum,
                         int* __restrict__ rowptr, int* __restrict__ cnt,
                         float* __restrict__ inv0, float* __restrict__ inv1,
                         float* __restrict__ inv2) {
    __shared__ int sm[SCAN_B];
    int i = blockIdx.x * SCAN_B + threadIdx.x;
    int v = (i < N_NODES) ? degi[i] : 0;
    sm[threadIdx.x] = v; __syncthreads();
    for (int s = 1; s < SCAN_B; s <<= 1) {
        int a = (threadIdx.x >= (unsigned)s) ? sm[threadIdx.x - s] : 0;
        __syncthreads();
        sm[threadIdx.x] += a;
        __syncthreads();
    }
    if (i < N_NODES) {
        int excl = bsum[blockIdx.x] + sm[threadIdx.x] - v;
        rowptr[i] = excl;
        cnt[i] = excl;
        float d = (float)v;
        inv0[i] = (v > 0) ? 1.0f / d : 0.0f;
        inv1[i] = 1.0f / (d + 1.0f);
        inv2[i] = 1.0f / (d + 2.0f);
    }
}

__global__ void k_fill(const int* __restrict__ src, const int* __restrict__ dst,
                       int* __restrict__ cnt, int* __restrict__ col) {
    int e = blockIdx.x * 256 + threadIdx.x;
    if (e < N_EDGES) {
        int pos = atomicAdd(&cnt[src[e]], 1);
        col[pos] = dst[e];
    }
}

// Wp[l][cg(2)][kh(2)][kb4(4)][ntp(8)][lane(64)][j(8)] = W[k][n]
//   kb = kh*4+kb4; k = kb*32 + (lane>>4)*8 + j
//   nt = ntp<4 ? cg*4+ntp : 8 + cg*4 + (ntp-4);  n = nt*16 + (lane&15)
//   (block cg stages its gamma tiles AND the paired beta tiles contiguously, 32 KB per kh)
__global__ void k_pack(const float* __restrict__ G1, const float* __restrict__ G2,
                       const float* __restrict__ B1, const float* __restrict__ B2,
                       short* __restrict__ Wp) {
    int idx = blockIdx.x * 256 + threadIdx.x;  // 3*65536 = 196608 total
    int j = idx & 7;
    int lane = (idx >> 3) & 63;
    int ntp = (idx >> 9) & 7;
    int kb4 = (idx >> 12) & 3;
    int kh = (idx >> 14) & 1;
    int cg = (idx >> 15) & 1;
    int l = idx >> 16;
    int k = (kh * 4 + kb4) * 32 + (lane >> 4) * 8 + j;
    int nt = (ntp < 4) ? (cg * 4 + ntp) : (8 + cg * 4 + (ntp - 4));
    int n = nt * 16 + (lane & 15);
    float v;
    if (n < 128) {
        v = (k < 128) ? G1[(l * 128 + n) * 128 + k] : G2[(l * 128 + n) * 128 + (k - 128)];
    } else {
        int n2 = n - 128;
        v = (k < 128) ? B1[(l * 128 + n2) * 128 + k] : B2[(l * 128 + n2) * 128 + (k - 128)];
    }
    Wp[idx] = (short)f2bf(v);
}

__global__ void k_xcast(const float* __restrict__ x, unsigned short* __restrict__ xb) {
    int i = (blockIdx.x * 256 + threadIdx.x) * 4;
    f32x4 v = *(const f32x4*)(x + i);
    unsigned short o0 = f2bf(v[0]), o1 = f2bf(v[1]), o2 = f2bf(v[2]), o3 = f2bf(v[3]);
    unsigned long long pk = (unsigned long long)o0 | ((unsigned long long)o1 << 16)
                          | ((unsigned long long)o2 << 32) | ((unsigned long long)o3 << 48);
    *(unsigned long long*)(xb + i) = pk;
}

// ---------------- gather: 4 rows per wave, 16B loads, shfl-broadcast cols, 4x unroll ----------------

__device__ __forceinline__ void gather4(const u16x8* __restrict__ h8,
        const int* __restrict__ col, int start, int d, int lane, float* acc) {
    int c = lane & 15;
    int base = lane & 48;
    int dd = d < 16 ? d : 16;
    int idx = (c < dd) ? col[start + c] : 0;
    int dm = d;
    int tmx = __shfl_xor(dm, 16);
    dm = dm > tmx ? dm : tmx;
    tmx = __shfl_xor(dm, 32);
    dm = dm > tmx ? dm : tmx;          // wave-uniform max degree of the 4 rows
    int dmain = dm < 16 ? dm : 16;
    int e = 0;
    for (; e + 4 <= dmain; e += 4) {
        int c0 = __shfl(idx, base + e, 64);
        int c1 = __shfl(idx, base + e + 1, 64);
        int c2 = __shfl(idx, base + e + 2, 64);
        int c3 = __shfl(idx, base + e + 3, 64);
        if (e < d) {
            u16x8 v = h8[(size_t)c0 * 16 + c];
#pragma unroll
            for (int j = 0; j < 8; ++j) acc[j] += bf2f(v[j]);
        }
        if (e + 1 < d) {
            u16x8 v = h8[(size_t)c1 * 16 + c];
#pragma unroll
            for (int j = 0; j < 8; ++j) acc[j] += bf2f(v[j]);
        }
        if (e + 2 < d) {
            u16x8 v = h8[(size_t)c2 * 16 + c];
#pragma unroll
            for (int j = 0; j < 8; ++j) acc[j] += bf2f(v[j]);
        }
        if (e + 3 < d) {
            u16x8 v = h8[(size_t)c3 * 16 + c];
#pragma unroll
            for (int j = 0; j < 8; ++j) acc[j] += bf2f(v[j]);
        }
    }
    for (; e < dmain; ++e) {
        int c0 = __shfl(idx, base + e, 64);
        if (e < d) {
            u16x8 v = h8[(size_t)c0 * 16 + c];
#pragma unroll
            for (int j = 0; j < 8; ++j) acc[j] += bf2f(v[j]);
        }
    }
    if (dm > 16) {  // cold path: deg > 16
        for (; e < d; ++e) {
            int c0 = col[start + e];
            u16x8 v = h8[(size_t)c0 * 16 + c];
#pragma unroll
            for (int j = 0; j < 8; ++j) acc[j] += bf2f(v[j]);
        }
    }
}

// ---------------- agg kernels ----------------

// shared hop-0: Sb = bf16(S(x)), Nb = bf16(inv0*S), hA = bf16(inv1*(S+x))
__global__ __launch_bounds__(256) void k_agg0(
    const unsigned short* __restrict__ xb, unsigned short* __restrict__ Sb,
    unsigned short* __restrict__ Nb, unsigned short* __restrict__ hA,
    const float* __restrict__ inv0, const float* __restrict__ inv1,
    const int* __restrict__ rowptr, const int* __restrict__ degi,
    const int* __restrict__ col)
{
    int lane = threadIdx.x & 63;
    int wid = (blockIdx.x * 256 + threadIdx.x) >> 6;
    int g = lane >> 4, c = lane & 15;
    int row = wid * 4 + g;              // grid exact: 6250*4*4 = 100000
    int start = rowptr[row], d = degi[row];
    u16x8 hv = ((const u16x8*)xb)[(size_t)row * 16 + c];
    float w0 = inv0[row], w1 = inv1[row];
    float acc[8] = {0,0,0,0,0,0,0,0};
    gather4((const u16x8*)xb, col, start, d, lane, acc);
    u16x8 so, no, ho;
#pragma unroll
    for (int j = 0; j < 8; ++j) {
        so[j] = f2bf(acc[j]);
        no[j] = f2bf(w0 * acc[j]);
        ho[j] = f2bf(w1 * (acc[j] + bf2f(hv[j])));
    }
    ((u16x8*)Sb)[(size_t)row * 16 + c] = so;
    ((u16x8*)Nb)[(size_t)row * 16 + c] = no;
    ((u16x8*)hA)[(size_t)row * 16 + c] = ho;
}

// head hops: h_next = inv1*(S+h); final emits emb = 0.25*(x+h1+h2+h3) -> out (ALL rows)
__global__ __launch_bounds__(256) void k_agg_head4(
    const unsigned short* __restrict__ hsrc, unsigned short* __restrict__ hnext,
    const unsigned short* __restrict__ xb, const unsigned short* __restrict__ h1b,
    float* __restrict__ outp, const float* __restrict__ inv1,
    const int* __restrict__ rowptr, const int* __restrict__ degi,
    const int* __restrict__ col, int final_hop)
{
    int lane = threadIdx.x & 63;
    int wid = (blockIdx.x * 256 + threadIdx.x) >> 6;
    int g = lane >> 4, c = lane & 15;
    int row = wid * 4 + g;
    int start = rowptr[row], d = degi[row];
    u16x8 hv = ((const u16x8*)hsrc)[(size_t)row * 16 + c];
    float w = inv1[row];
    float acc[8] = {0,0,0,0,0,0,0,0};
    gather4((const u16x8*)hsrc, col, start, d, lane, acc);
    float hn[8];
#pragma unroll
    for (int j = 0; j < 8; ++j) hn[j] = w * (acc[j] + bf2f(hv[j]));
    if (!final_hop) {
        u16x8 ho;
#pragma unroll
        for (int j = 0; j < 8; ++j) ho[j] = f2bf(hn[j]);
        ((u16x8*)hnext)[(size_t)row * 16 + c] = ho;
    } else {
        u16x8 xv = ((const u16x8*)xb)[(size_t)row * 16 + c];
        u16x8 h1 = ((const u16x8*)h1b)[(size_t)row * 16 + c];
        f32x4 e0, e1;
#pragma unroll
        for (int j = 0; j < 4; ++j)
            e0[j] = 0.25f * (bf2f(xv[j]) + bf2f(h1[j]) + bf2f(hv[j]) + hn[j]);
#pragma unroll
        for (int j = 0; j < 4; ++j)
            e1[j] = 0.25f * (bf2f(xv[4 + j]) + bf2f(h1[4 + j]) + bf2f(hv[4 + j]) + hn[4 + j]);
        float* op = outp + (size_t)row * DIM + c * 8;
        *(f32x4*)op = e0;
        *(f32x4*)(op + 4) = e1;
    }
}

// tail agg: Sb = bf16(raw sum), Nb = bf16(inv0*sum)
__global__ __launch_bounds__(256) void k_agg_tail4(
    const unsigned short* __restrict__ hsrc, unsigned short* __restrict__ Sb,
    unsigned short* __restrict__ Nb, const float* __restrict__ inv0,
    const int* __restrict__ rowptr, const int* __restrict__ degi,
    const int* __restrict__ col)
{
    int lane = threadIdx.x & 63;
    int wid = (blockIdx.x * 256 + threadIdx.x) >> 6;
    int g = lane >> 4, c = lane & 15;
    int row = wid * 4 + g;
    int start = rowptr[row], d = degi[row];
    float w0 = inv0[row];
    float acc[8] = {0,0,0,0,0,0,0,0};
    gather4((const u16x8*)hsrc, col, start, d, lane, acc);
    u16x8 so, no;
#pragma unroll
    for (int j = 0; j < 8; ++j) {
        so[j] = f2bf(acc[j]);
        no[j] = f2bf(w0 * acc[j]);
    }
    ((u16x8*)Sb)[(size_t)row * 16 + c] = so;
    ((u16x8*)Nb)[(size_t)row * 16 + c] = no;
}

// ---------------- tail GEMM + update: 32 rows/wave, 64 out-cols/block ----------------
// block (rb, cg): rows rb*128..+128 (4 waves x 32), out cols [cg*64, cg*64+64).
// Z-cols staged: gamma tiles cg*4..+4 AND beta tiles 8+cg*4..+4 (paired), per K-half 32 KB LDS.
// A: kh=0 from h (bf16), kh=1 from Nb = bf16(inv0*S) -- no converts in K-loop.
// Epilogue identical math to R5; wave-private LDS transpose, zero barriers.
__global__ __launch_bounds__(256) void k_gemm_tail(
    const unsigned short* __restrict__ hb, const unsigned short* __restrict__ Sb,
    const unsigned short* __restrict__ Nb,
    unsigned short* __restrict__ hb_next,
    const unsigned short* __restrict__ xb, const unsigned short* __restrict__ t1b,
    float* __restrict__ outp,
    const float* __restrict__ Rl, const short* __restrict__ Wp,
    const float* __restrict__ inv0, const float* __restrict__ inv2,
    const int* __restrict__ degi, int last)
{
    __shared__ __align__(16) char smraw[33792];
    short* smW = (short*)smraw;

    int wave = threadIdx.x >> 6, lane = threadIdx.x & 63;
    int quad = lane >> 4, m16 = lane & 15;
    int cg = blockIdx.x & 1;
    int rb = blockIdx.x >> 1;
    int r0 = rb * 128 + wave * 32;

    const unsigned short* arow[2][2];
#pragma unroll
    for (int rf = 0; rf < 2; ++rf) {
        int rA = r0 + rf * 16 + m16;
        int cA = rA < N_NODES ? rA : N_NODES - 1;
        arow[0][rf] = hb + (size_t)cA * DIM;
        arow[1][rf] = Nb + (size_t)cA * DIM;
    }

    f32x4 acc[2][8];
    const f32x4 vz = {0.f, 0.f, 0.f, 0.f};
#pragma unroll
    for (int rf = 0; rf < 2; ++rf)
#pragma unroll
        for (int t = 0; t < 8; ++t) acc[rf][t] = vz;

#pragma unroll
    for (int kh = 0; kh < 2; ++kh) {
        if (kh) __syncthreads();           // all reads of previous half done
        {   // stage this K-half's 32 KB of B
            const int4* g = (const int4*)(Wp + (cg * 2 + kh) * 16384);
            int4* sd = (int4*)smW;
#pragma unroll
            for (int jj = 0; jj < 8; ++jj)
                sd[jj * 256 + threadIdx.x] = g[jj * 256 + threadIdx.x];
        }
        __syncthreads();
#pragma unroll
        for (int kb4 = 0; kb4 < 4; ++kb4) {
            bf16x8 a0 = *(const bf16x8*)(arow[kh][0] + kb4 * 32 + quad * 8);
            bf16x8 a1 = *(const bf16x8*)(arow[kh][1] + kb4 * 32 + quad * 8);
            const short* wb = smW + kb4 * 4096 + lane * 8;
#pragma unroll
            for (int ntp = 0; ntp < 8; ++ntp) {
                bf16x8 b = *(const bf16x8*)(wb + ntp * 512);
                acc[0][ntp] = __builtin_amdgcn_mfma_f32_16x16x32_bf16(a0, b, acc[0][ntp], 0, 0, 0);
                acc[1][ntp] = __builtin_amdgcn_mfma_f32_16x16x32_bf16(a1, b, acc[1][ntp], 0, 0, 0);
            }
        }
    }
    __syncthreads();   // B reads done before LDS reuse as zbw

    // epilogue: C/D layout col=m16, row=quad*4+r; wave-private transpose buffer
    float* zbw = (float*)smraw + wave * (16 * 132);   // 8448 B per wave, 33792 total
    int cl = lane & 15, gg = lane >> 4;
    int c4 = cl * 4;
    int colbase = cg * 64;
    f32x4 Rv = *(const f32x4*)(Rl + colbase + c4);

#pragma unroll
    for (int rf = 0; rf < 2; ++rf) {
#pragma unroll
        for (int ntp = 0; ntp < 8; ++ntp) {
            int cofs = (ntp < 4) ? ntp * 16 : 64 + (ntp - 4) * 16;
#pragma unroll
            for (int r = 0; r < 4; ++r)
                zbw[(quad * 4 + r) * 132 + cofs + m16] = acc[rf][ntp][r];
        }
        // same-wave LDS ordering (lgkmcnt) -- no barrier needed
#pragma unroll
        for (int p = 0; p < 4; ++p) {
            int lr = p * 4 + gg;
            int gi = r0 + rf * 16 + lr;
            if (gi < N_NODES) {
                f32x4 z1 = *(const f32x4*)&zbw[lr * 132 + c4];
                f32x4 z2 = *(const f32x4*)&zbw[lr * 132 + 64 + c4];
                size_t o = (size_t)gi * DIM + colbase + c4;
                u16x4 hu = *(const u16x4*)(hb + o);
                u16x4 su = *(const u16x4*)(Sb + o);
                float wi0 = inv0[gi], wi2 = inv2[gi];
                f32x4 hn, hvf;
#pragma unroll
                for (int j = 0; j < 4; ++j) {
                    float h = bf2f(hu[j]);
                    float sva = bf2f(su[j]);
                    float nb = wi0 * sva;
                    float g = (z1[j] > 0.f ? z1[j] : 0.2f * z1[j]) + 1.0f;
                    float be = (z2[j] > 0.f ? z2[j] : 0.2f * z2[j]);
                    float mm = h + g * Rv[j] + be - nb;
                    hn[j] = wi2 * (sva + h + mm);
                    hvf[j] = h;
                }
                if (!last) {
                    u16x4 ou;
#pragma unroll
                    for (int j = 0; j < 4; ++j) ou[j] = f2bf(hn[j]);
                    *(u16x4*)(hb_next + o) = ou;
                } else if (degi[gi] <= 5) {
                    u16x4 xu  = *(const u16x4*)(xb  + o);
                    u16x4 t1u = *(const u16x4*)(t1b + o);
                    f32x4 ev;
#pragma unroll
                    for (int j = 0; j < 4; ++j)
                        ev[j] = 0.25f * (bf2f(xu[j]) + bf2f(t1u[j]) + hvf[j] + hn[j]);
                    *(f32x4*)(outp + o) = ev;
                }
            }
        }
    }
}

// ---------------- launch ----------------

extern "C" void kernel_launch(void* const* d_in, const int* in_sizes, int n_in,
                              void* d_out, int out_size, void* d_ws, size_t ws_size,
                              hipStream_t stream) {
    const float* x  = (const float*)d_in[0];
    const float* G1 = (const float*)d_in[1];
    const float* G2 = (const float*)d_in[2];
    const float* B1 = (const float*)d_in[3];
    const float* B2 = (const float*)d_in[4];
    const float* R  = (const float*)d_in[5];
    const int* esrc = (const int*)d_in[6];
    const int* edst = (const int*)d_in[7];
    float* out = (float*)d_out;

    char* base = (char*)d_ws;
    size_t off = 0;
    auto alloc = [&](size_t b) -> void* {
        void* p = base + off;
        off = (off + b + 255) & ~(size_t)255;
        return p;
    };
    int* degi   = (int*)alloc(4 * N_NODES);
    int* rowptr = (int*)alloc(4 * N_NODES);
    int* cnt    = (int*)alloc(4 * N_NODES);
    int* bsum   = (int*)alloc(4 * 256);
    int* col    = (int*)alloc(4 * N_EDGES);
    float* inv0 = (float*)alloc(4 * N_NODES);
    float* inv1 = (float*)alloc(4 * N_NODES);
    float* inv2 = (float*)alloc(4 * N_NODES);
    short* Wp   = (short*)alloc(2 * 3 * 65536);
    unsigned short* xb = (unsigned short*)alloc(2ull * N_NODES * DIM);
    unsigned short* hA = (unsigned short*)alloc(2ull * N_NODES * DIM);  // head h1
    unsigned short* hC = (unsigned short*)alloc(2ull * N_NODES * DIM);  // head h2, later tail t2
    unsigned short* tA = (unsigned short*)alloc(2ull * N_NODES * DIM);  // tail t1
    unsigned short* Sb = (unsigned short*)alloc(2ull * N_NODES * DIM);  // bf16 row sums
    unsigned short* Nb = (unsigned short*)alloc(2ull * N_NODES * DIM);  // bf16 inv0*sums
    unsigned short* tB = hC;   // alias: hC dead after head final; tail t2 born after

    hipMemsetAsync(degi, 0, 4 * N_NODES, stream);
    k_degree<<<(N_EDGES + 255) / 256, 256, 0, stream>>>(esrc, degi);
    k_chunksum<<<NCHUNK, SCAN_B, 0, stream>>>(degi, bsum);
    k_scanb<<<1, 128, 0, stream>>>(bsum, NCHUNK);
    k_rowptr<<<NCHUNK, SCAN_B, 0, stream>>>(degi, bsum, rowptr, cnt, inv0, inv1, inv2);
    k_fill<<<(N_EDGES + 255) / 256, 256, 0, stream>>>(esrc, edst, cnt, col);
    k_pack<<<768, 256, 0, stream>>>(G1, G2, B1, B2, Wp);
    k_xcast<<<12500, 256, 0, stream>>>(x, xb);

    // hop 0 shared: Sb, Nb, head h1
    k_agg0<<<AGG_BLOCKS, 256, 0, stream>>>(xb, Sb, Nb, hA, inv0, inv1, rowptr, degi, col);

    // tail hop 0 GEMM -> t1
    k_gemm_tail<<<GEMM_BLOCKS, 256, 0, stream>>>(xb, Sb, Nb, tA, xb, tA, out, R, Wp, inv0, inv2, degi, 0);

    // head hops 1,2 (final writes emb for ALL rows)
    k_agg_head4<<<AGG_BLOCKS, 256, 0, stream>>>(hA, hC, xb, hA, out, inv1, rowptr, degi, col, 0);
    k_agg_head4<<<AGG_BLOCKS, 256, 0, stream>>>(hC, hC, xb, hA, out, inv1, rowptr, degi, col, 1);

    // tail hop 1: agg(t1) -> Sb,Nb; GEMM -> t2 (reuses hC)
    k_agg_tail4<<<AGG_BLOCKS, 256, 0, stream>>>(tA, Sb, Nb, inv0, rowptr, degi, col);
    k_gemm_tail<<<GEMM_BLOCKS, 256, 0, stream>>>(tA, Sb, Nb, tB, xb, tA, out, R + 128, Wp + 65536, inv0, inv2, degi, 0);

    // tail hop 2: agg(t2) -> Sb,Nb; GEMM -> out (deg<=5 rows)
    k_agg_tail4<<<AGG_BLOCKS, 256, 0, stream>>>(tB, Sb, Nb, inv0, rowptr, degi, col);
    k_gemm_tail<<<GEMM_BLOCKS, 256, 0, stream>>>(tB, Sb, Nb, tB, xb, tA, out, R + 256, Wp + 131072, inv0, inv2, degi, 1);
}

// Round 8
// 494.267 us; speedup vs baseline: 1.0211x; 1.0211x over previous
//
#include <hip/hip_runtime.h>

#define N_NODES 100000
#define N_EDGES 600000
#define DIM 128
#define SCAN_B 1024
#define NCHUNK 98    // ceil(100000/1024)
#define AGG_BLOCKS 6250
#define GEMM_RGP 784           // padded row-group pairs (784*2*64 = 100352; 784%8==0 -> XCD affinity)
#define GEMM_NRG 1563          // ceil(100000/64) row-groups
#define GEMM_BLOCKS (4 * GEMM_RGP)

typedef __attribute__((ext_vector_type(4))) float f32x4;
typedef __attribute__((ext_vector_type(8))) short bf16x8;
typedef __attribute__((ext_vector_type(4))) unsigned short u16x4;
typedef __attribute__((ext_vector_type(8))) unsigned short u16x8;

__device__ __forceinline__ unsigned short f2bf(float f) {
    union { float f; unsigned u; } cv; cv.f = f;
    unsigned r = (cv.u + 0x7FFFu + ((cv.u >> 16) & 1u)) >> 16;
    return (unsigned short)r;
}
__device__ __forceinline__ float bf2f(unsigned short v) {
    union { unsigned u; float f; } c; c.u = ((unsigned)v) << 16; return c.f;
}

// ---------------- setup: degree / scan / csr fill / weight pack ----------------

__global__ void k_degree(const int* __restrict__ src, int* __restrict__ degi) {
    int e = blockIdx.x * 256 + threadIdx.x;
    if (e < N_EDGES) atomicAdd(&degi[src[e]], 1);
}

__global__ void k_chunksum(const int* __restrict__ degi, int* __restrict__ bsum) {
    __shared__ int sm[SCAN_B];
    int i = blockIdx.x * SCAN_B + threadIdx.x;
    sm[threadIdx.x] = (i < N_NODES) ? degi[i] : 0;
    __syncthreads();
    for (int s = SCAN_B / 2; s > 0; s >>= 1) {
        if (threadIdx.x < (unsigned)s) sm[threadIdx.x] += sm[threadIdx.x + s];
        __syncthreads();
    }
    if (threadIdx.x == 0) bsum[blockIdx.x] = sm[0];
}

__global__ void k_scanb(int* __restrict__ bsum, int nb) {
    __shared__ int sm[128];
    int t = threadIdx.x;
    int v = (t < nb) ? bsum[t] : 0;
    sm[t] = v; __syncthreads();
    for (int s = 1; s < 128; s <<= 1) {
        int a = (t >= s) ? sm[t - s] : 0;
        __syncthreads();
        sm[t] += a;
        __syncthreads();
    }
    if (t < nb) bsum[t] = sm[t] - v;  // exclusive
}

__global__ void k_rowptr(const int* __restrict__ degi, const int* __restrict__ bsum,
                         int* __restrict__ rowptr, int* __restrict__ cnt,
                         float* __restrict__ inv0, float* __restrict__ inv1,
                         float* __restrict__ inv2) {
    __shared__ int sm[SCAN_B];
    int i = blockIdx.x * SCAN_B + threadIdx.x;
    int v = (i < N_NODES) ? degi[i] : 0;
    sm[threadIdx.x] = v; __syncthreads();
    for (int s = 1; s < SCAN_B; s <<= 1) {
        int a = (threadIdx.x >= (unsigned)s) ? sm[threadIdx.x - s] : 0;
        __syncthreads();
        sm[threadIdx.x] += a;
        __syncthreads();
    }
    if (i < N_NODES) {
        int excl = bsum[blockIdx.x] + sm[threadIdx.x] - v;
        rowptr[i] = excl;
        cnt[i] = excl;
        float d = (float)v;
        inv0[i] = (v > 0) ? 1.0f / d : 0.0f;
        inv1[i] = 1.0f / (d + 1.0f);
        inv2[i] = 1.0f / (d + 2.0f);
    }
}

__global__ void k_fill(const int* __restrict__ src, const int* __restrict__ dst,
                       int* __restrict__ cnt, int* __restrict__ col) {
    int e = blockIdx.x * 256 + threadIdx.x;
    if (e < N_EDGES) {
        int pos = atomicAdd(&cnt[src[e]], 1);
        col[pos] = dst[e];
    }
}

// Wp[l][cg(4)][kb(8)][ntp(4)][lane(64)][j(8)] = W[k][n]
//   k = kb*32 + (lane>>4)*8 + j
//   nt = ntp<2 ? cg*2+ntp : 8 + cg*2 + (ntp-2);  n = nt*16 + (lane&15)
//   (gamma tiles cg*2..+2 and paired beta tiles 8+cg*2..+2 per col-group)
__global__ void k_pack(const float* __restrict__ G1, const float* __restrict__ G2,
                       const float* __restrict__ B1, const float* __restrict__ B2,
                       short* __restrict__ Wp) {
    int idx = blockIdx.x * 256 + threadIdx.x;  // 3*65536 = 196608 total
    int j = idx & 7;
    int lane = (idx >> 3) & 63;
    int ntp = (idx >> 9) & 3;
    int kb = (idx >> 11) & 7;
    int cg = (idx >> 14) & 3;
    int l = idx >> 16;
    int k = kb * 32 + (lane >> 4) * 8 + j;
    int nt = (ntp < 2) ? (cg * 2 + ntp) : (8 + cg * 2 + (ntp - 2));
    int n = nt * 16 + (lane & 15);
    float v;
    if (n < 128) {
        v = (k < 128) ? G1[(l * 128 + n) * 128 + k] : G2[(l * 128 + n) * 128 + (k - 128)];
    } else {
        int n2 = n - 128;
        v = (k < 128) ? B1[(l * 128 + n2) * 128 + k] : B2[(l * 128 + n2) * 128 + (k - 128)];
    }
    Wp[idx] = (short)f2bf(v);
}

__global__ void k_xcast(const float* __restrict__ x, unsigned short* __restrict__ xb) {
    int i = (blockIdx.x * 256 + threadIdx.x) * 4;
    f32x4 v = *(const f32x4*)(x + i);
    unsigned short o0 = f2bf(v[0]), o1 = f2bf(v[1]), o2 = f2bf(v[2]), o3 = f2bf(v[3]);
    unsigned long long pk = (unsigned long long)o0 | ((unsigned long long)o1 << 16)
                          | ((unsigned long long)o2 << 32) | ((unsigned long long)o3 << 48);
    *(unsigned long long*)(xb + i) = pk;
}

// ---------------- gather: 4 rows per wave, 16B loads, shfl-broadcast cols, 4x unroll ----------------

__device__ __forceinline__ void gather4(const u16x8* __restrict__ h8,
        const int* __restrict__ col, int start, int d, int lane, float* acc) {
    int c = lane & 15;
    int base = lane & 48;
    int dd = d < 16 ? d : 16;
    int idx = (c < dd) ? col[start + c] : 0;
    int dm = d;
    int tmx = __shfl_xor(dm, 16);
    dm = dm > tmx ? dm : tmx;
    tmx = __shfl_xor(dm, 32);
    dm = dm > tmx ? dm : tmx;          // wave-uniform max degree of the 4 rows
    int dmain = dm < 16 ? dm : 16;
    int e = 0;
    for (; e + 4 <= dmain; e += 4) {
        int c0 = __shfl(idx, base + e, 64);
        int c1 = __shfl(idx, base + e + 1, 64);
        int c2 = __shfl(idx, base + e + 2, 64);
        int c3 = __shfl(idx, base + e + 3, 64);
        if (e < d) {
            u16x8 v = h8[(size_t)c0 * 16 + c];
#pragma unroll
            for (int j = 0; j < 8; ++j) acc[j] += bf2f(v[j]);
        }
        if (e + 1 < d) {
            u16x8 v = h8[(size_t)c1 * 16 + c];
#pragma unroll
            for (int j = 0; j < 8; ++j) acc[j] += bf2f(v[j]);
        }
        if (e + 2 < d) {
            u16x8 v = h8[(size_t)c2 * 16 + c];
#pragma unroll
            for (int j = 0; j < 8; ++j) acc[j] += bf2f(v[j]);
        }
        if (e + 3 < d) {
            u16x8 v = h8[(size_t)c3 * 16 + c];
#pragma unroll
            for (int j = 0; j < 8; ++j) acc[j] += bf2f(v[j]);
        }
    }
    for (; e < dmain; ++e) {
        int c0 = __shfl(idx, base + e, 64);
        if (e < d) {
            u16x8 v = h8[(size_t)c0 * 16 + c];
#pragma unroll
            for (int j = 0; j < 8; ++j) acc[j] += bf2f(v[j]);
        }
    }
    if (dm > 16) {  // cold path: deg > 16
        for (; e < d; ++e) {
            int c0 = col[start + e];
            u16x8 v = h8[(size_t)c0 * 16 + c];
#pragma unroll
            for (int j = 0; j < 8; ++j) acc[j] += bf2f(v[j]);
        }
    }
}

// ---------------- agg kernels ----------------

// shared hop-0: Nb = bf16(inv0*S(x)), hA = bf16(inv1*(S+x))
__global__ __launch_bounds__(256) void k_agg0(
    const unsigned short* __restrict__ xb, unsigned short* __restrict__ Nb,
    unsigned short* __restrict__ hA,
    const float* __restrict__ inv0, const float* __restrict__ inv1,
    const int* __restrict__ rowptr, const int* __restrict__ degi,
    const int* __restrict__ col)
{
    int lane = threadIdx.x & 63;
    int wid = (blockIdx.x * 256 + threadIdx.x) >> 6;
    int g = lane >> 4, c = lane & 15;
    int row = wid * 4 + g;              // grid exact: 6250*4*4 = 100000
    int start = rowptr[row], d = degi[row];
    u16x8 hv = ((const u16x8*)xb)[(size_t)row * 16 + c];
    float w0 = inv0[row], w1 = inv1[row];
    float acc[8] = {0,0,0,0,0,0,0,0};
    gather4((const u16x8*)xb, col, start, d, lane, acc);
    u16x8 no, ho;
#pragma unroll
    for (int j = 0; j < 8; ++j) {
        no[j] = f2bf(w0 * acc[j]);
        ho[j] = f2bf(w1 * (acc[j] + bf2f(hv[j])));
    }
    ((u16x8*)Nb)[(size_t)row * 16 + c] = no;
    ((u16x8*)hA)[(size_t)row * 16 + c] = ho;
}

// head hops: h_next = inv1*(S+h); final emits emb = 0.25*(x+h1+h2+h3) -> out (ALL rows)
__global__ __launch_bounds__(256) void k_agg_head4(
    const unsigned short* __restrict__ hsrc, unsigned short* __restrict__ hnext,
    const unsigned short* __restrict__ xb, const unsigned short* __restrict__ h1b,
    float* __restrict__ outp, const float* __restrict__ inv1,
    const int* __restrict__ rowptr, const int* __restrict__ degi,
    const int* __restrict__ col, int final_hop)
{
    int lane = threadIdx.x & 63;
    int wid = (blockIdx.x * 256 + threadIdx.x) >> 6;
    int g = lane >> 4, c = lane & 15;
    int row = wid * 4 + g;
    int start = rowptr[row], d = degi[row];
    u16x8 hv = ((const u16x8*)hsrc)[(size_t)row * 16 + c];
    float w = inv1[row];
    float acc[8] = {0,0,0,0,0,0,0,0};
    gather4((const u16x8*)hsrc, col, start, d, lane, acc);
    float hn[8];
#pragma unroll
    for (int j = 0; j < 8; ++j) hn[j] = w * (acc[j] + bf2f(hv[j]));
    if (!final_hop) {
        u16x8 ho;
#pragma unroll
        for (int j = 0; j < 8; ++j) ho[j] = f2bf(hn[j]);
        ((u16x8*)hnext)[(size_t)row * 16 + c] = ho;
    } else {
        u16x8 xv = ((const u16x8*)xb)[(size_t)row * 16 + c];
        u16x8 h1 = ((const u16x8*)h1b)[(size_t)row * 16 + c];
        f32x4 e0, e1;
#pragma unroll
        for (int j = 0; j < 4; ++j)
            e0[j] = 0.25f * (bf2f(xv[j]) + bf2f(h1[j]) + bf2f(hv[j]) + hn[j]);
#pragma unroll
        for (int j = 0; j < 4; ++j)
            e1[j] = 0.25f * (bf2f(xv[4 + j]) + bf2f(h1[4 + j]) + bf2f(hv[4 + j]) + hn[4 + j]);
        float* op = outp + (size_t)row * DIM + c * 8;
        *(f32x4*)op = e0;
        *(f32x4*)(op + 4) = e1;
    }
}

// tail agg: Nb = bf16(inv0 * raw sum)
__global__ __launch_bounds__(256) void k_agg_tail4(
    const unsigned short* __restrict__ hsrc, unsigned short* __restrict__ Nb,
    const float* __restrict__ inv0,
    const int* __restrict__ rowptr, const int* __restrict__ degi,
    const int* __restrict__ col)
{
    int lane = threadIdx.x & 63;
    int wid = (blockIdx.x * 256 + threadIdx.x) >> 6;
    int g = lane >> 4, c = lane & 15;
    int row = wid * 4 + g;
    int start = rowptr[row], d = degi[row];
    float w0 = inv0[row];
    float acc[8] = {0,0,0,0,0,0,0,0};
    gather4((const u16x8*)hsrc, col, start, d, lane, acc);
    u16x8 no;
#pragma unroll
    for (int j = 0; j < 8; ++j) no[j] = f2bf(w0 * acc[j]);
    ((u16x8*)Nb)[(size_t)row * 16 + c] = no;
}

// ---------------- tail GEMM + update: wave-independent, zero barriers ----------------
// Each wave: 64 rows (4 rf) x 32 out-cols (Z-tiles: 2 gamma + 2 beta), 128 MFMAs.
// B straight from L2 (Wp is 128 KB, L2-resident). A: kb<4 from h, kb>=4 from Nb=bf16(inv0*S).
// S recomputed in epilogue as N*deg (Sb eliminated). Wave-private LDS transpose, no syncs.
// Grid: cg-major over 784-padded row-group pairs -> all 4 cgs of a row on one XCD.
__global__ __launch_bounds__(128, 4) void k_gemm_tail(
    const unsigned short* __restrict__ hb, const unsigned short* __restrict__ Nb,
    unsigned short* __restrict__ hb_next,
    const unsigned short* __restrict__ xb, const unsigned short* __restrict__ t1b,
    float* __restrict__ outp,
    const float* __restrict__ Rl, const short* __restrict__ Wp,
    const float* __restrict__ inv2, const int* __restrict__ degi, int last)
{
    __shared__ __align__(16) float zs[2][16][68];
    int wave = threadIdx.x >> 6, lane = threadIdx.x & 63;
    int cg = blockIdx.x / GEMM_RGP;
    int rgp = blockIdx.x % GEMM_RGP;
    int rg = rgp * 2 + wave;
    if (rg >= GEMM_NRG) return;        // wave-uniform exit; no barriers in kernel
    int r0 = rg * 64;
    int quad = lane >> 4, m16 = lane & 15;

    const unsigned short* hrow[4];
    const unsigned short* nrow[4];
#pragma unroll
    for (int rf = 0; rf < 4; ++rf) {
        int rA = r0 + rf * 16 + m16;
        int cA = rA < N_NODES ? rA : N_NODES - 1;
        hrow[rf] = hb + (size_t)cA * DIM;
        nrow[rf] = Nb + (size_t)cA * DIM;
    }

    f32x4 acc[4][4];
    const f32x4 vz = {0.f, 0.f, 0.f, 0.f};
#pragma unroll
    for (int rf = 0; rf < 4; ++rf)
#pragma unroll
        for (int t = 0; t < 4; ++t) acc[rf][t] = vz;

    const short* wpl = Wp + cg * 16384;
#pragma unroll
    for (int kb = 0; kb < 8; ++kb) {
        int ko = (kb & 3) * 32 + quad * 8;
        bf16x8 a[4];
        if (kb < 4) {
#pragma unroll
            for (int rf = 0; rf < 4; ++rf) a[rf] = *(const bf16x8*)(hrow[rf] + ko);
        } else {
#pragma unroll
            for (int rf = 0; rf < 4; ++rf) a[rf] = *(const bf16x8*)(nrow[rf] + ko);
        }
        const short* wb = wpl + kb * 2048 + lane * 8;
#pragma unroll
        for (int ntp = 0; ntp < 4; ++ntp) {
            bf16x8 b = *(const bf16x8*)(wb + ntp * 512);
#pragma unroll
            for (int rf = 0; rf < 4; ++rf)
                acc[rf][ntp] = __builtin_amdgcn_mfma_f32_16x16x32_bf16(a[rf], b, acc[rf][ntp], 0, 0, 0);
        }
    }

    // epilogue: C/D layout col=m16 (within tile), row=quad*4+r; wave-private transpose
    float (*zbw)[68] = zs[wave];
    int rl = lane >> 2;
    int c8 = (lane & 3) * 8;
    int colbase = cg * 32 + c8;
    f32x4 Rva = *(const f32x4*)(Rl + colbase);
    f32x4 Rvb = *(const f32x4*)(Rl + colbase + 4);

#pragma unroll
    for (int rf = 0; rf < 4; ++rf) {
#pragma unroll
        for (int ntp = 0; ntp < 4; ++ntp) {
            int cofs = (ntp < 2) ? ntp * 16 : 32 + (ntp - 2) * 16;
#pragma unroll
            for (int r = 0; r < 4; ++r)
                zbw[quad * 4 + r][cofs + m16] = acc[rf][ntp][r];
        }
        // same-wave LDS ordering (lgkmcnt) -- no barrier needed
        int gi = r0 + rf * 16 + rl;
        if (gi < N_NODES) {
            f32x4 z1a = *(const f32x4*)&zbw[rl][c8];
            f32x4 z1b = *(const f32x4*)&zbw[rl][c8 + 4];
            f32x4 z2a = *(const f32x4*)&zbw[rl][32 + c8];
            f32x4 z2b = *(const f32x4*)&zbw[rl][32 + c8 + 4];
            size_t o = (size_t)gi * DIM + colbase;
            u16x8 hu = *(const u16x8*)(hb + o);
            u16x8 nu = *(const u16x8*)(Nb + o);
            float wi2 = inv2[gi];
            int dg = degi[gi];
            float ddm1 = (float)dg - 1.0f;
            float hn[8], hvf[8];
#pragma unroll
            for (int j = 0; j < 8; ++j) {
                float z1 = (j < 4) ? z1a[j] : z1b[j - 4];
                float z2 = (j < 4) ? z2a[j] : z2b[j - 4];
                float rv = (j < 4) ? Rva[j] : Rvb[j - 4];
                float h = bf2f(hu[j]);
                float N = bf2f(nu[j]);
                float g = (z1 > 0.f ? z1 : 0.2f * z1) + 1.0f;
                float be = (z2 > 0.f ? z2 : 0.2f * z2);
                // hn = inv2*(S + h + m), m = h + g*R + be - N, S = N*deg
                hn[j] = wi2 * (N * ddm1 + 2.0f * h + g * rv + be);
                hvf[j] = h;
            }
            if (!last) {
                u16x8 ou;
#pragma unroll
                for (int j = 0; j < 8; ++j) ou[j] = f2bf(hn[j]);
                *(u16x8*)(hb_next + o) = ou;
            } else if (dg <= 5) {
                u16x8 xu  = *(const u16x8*)(xb  + o);
                u16x8 t1u = *(const u16x8*)(t1b + o);
                f32x4 e0, e1;
#pragma unroll
                for (int j = 0; j < 4; ++j)
                    e0[j] = 0.25f * (bf2f(xu[j]) + bf2f(t1u[j]) + hvf[j] + hn[j]);
#pragma unroll
                for (int j = 0; j < 4; ++j)
                    e1[j] = 0.25f * (bf2f(xu[4 + j]) + bf2f(t1u[4 + j]) + hvf[4 + j] + hn[4 + j]);
                float* op = outp + o;
                *(f32x4*)op = e0;
                *(f32x4*)(op + 4) = e1;
            }
        }
    }
}

// ---------------- launch ----------------

extern "C" void kernel_launch(void* const* d_in, const int* in_sizes, int n_in,
                              void* d_out, int out_size, void* d_ws, size_t ws_size,
                              hipStream_t stream) {
    const float* x  = (const float*)d_in[0];
    const float* G1 = (const float*)d_in[1];
    const float* G2 = (const float*)d_in[2];
    const float* B1 = (const float*)d_in[3];
    const float* B2 = (const float*)d_in[4];
    const float* R  = (const float*)d_in[5];
    const int* esrc = (const int*)d_in[6];
    const int* edst = (const int*)d_in[7];
    float* out = (float*)d_out;

    char* base = (char*)d_ws;
    size_t off = 0;
    auto alloc = [&](size_t b) -> void* {
        void* p = base + off;
        off = (off + b + 255) & ~(size_t)255;
        return p;
    };
    int* degi   = (int*)alloc(4 * N_NODES);
    int* rowptr = (int*)alloc(4 * N_NODES);
    int* cnt    = (int*)alloc(4 * N_NODES);
    int* bsum   = (int*)alloc(4 * 256);
    int* col    = (int*)alloc(4 * N_EDGES);
    float* inv0 = (float*)alloc(4 * N_NODES);
    float* inv1 = (float*)alloc(4 * N_NODES);
    float* inv2 = (float*)alloc(4 * N_NODES);
    short* Wp   = (short*)alloc(2 * 3 * 65536);
    unsigned short* xb = (unsigned short*)alloc(2ull * N_NODES * DIM);
    unsigned short* hA = (unsigned short*)alloc(2ull * N_NODES * DIM);  // head h1
    unsigned short* hC = (unsigned short*)alloc(2ull * N_NODES * DIM);  // head h2, later tail t2
    unsigned short* tA = (unsigned short*)alloc(2ull * N_NODES * DIM);  // tail t1
    unsigned short* Nb = (unsigned short*)alloc(2ull * N_NODES * DIM);  // bf16 inv0*sums
    unsigned short* tB = hC;   // alias: hC dead after head final; tail t2 born after

    hipMemsetAsync(degi, 0, 4 * N_NODES, stream);
    k_degree<<<(N_EDGES + 255) / 256, 256, 0, stream>>>(esrc, degi);
    k_chunksum<<<NCHUNK, SCAN_B, 0, stream>>>(degi, bsum);
    k_scanb<<<1, 128, 0, stream>>>(bsum, NCHUNK);
    k_rowptr<<<NCHUNK, SCAN_B, 0, stream>>>(degi, bsum, rowptr, cnt, inv0, inv1, inv2);
    k_fill<<<(N_EDGES + 255) / 256, 256, 0, stream>>>(esrc, edst, cnt, col);
    k_pack<<<768, 256, 0, stream>>>(G1, G2, B1, B2, Wp);
    k_xcast<<<12500, 256, 0, stream>>>(x, xb);

    // hop 0 shared: Nb(x) + head h1
    k_agg0<<<AGG_BLOCKS, 256, 0, stream>>>(xb, Nb, hA, inv0, inv1, rowptr, degi, col);

    // tail hop 0 GEMM -> t1
    k_gemm_tail<<<GEMM_BLOCKS, 128, 0, stream>>>(xb, Nb, tA, xb, tA, out, R, Wp, inv2, degi, 0);

    // head hops 1,2 (final writes emb for ALL rows)
    k_agg_head4<<<AGG_BLOCKS, 256, 0, stream>>>(hA, hC, xb, hA, out, inv1, rowptr, degi, col, 0);
    k_agg_head4<<<AGG_BLOCKS, 256, 0, stream>>>(hC, hC, xb, hA, out, inv1, rowptr, degi, col, 1);

    // tail hop 1: agg(t1) -> Nb; GEMM -> t2 (reuses hC)
    k_agg_tail4<<<AGG_BLOCKS, 256, 0, stream>>>(tA, Nb, inv0, rowptr, degi, col);
    k_gemm_tail<<<GEMM_BLOCKS, 128, 0, stream>>>(tA, Nb, tB, xb, tA, out, R + 128, Wp + 65536, inv2, degi, 0);

    // tail hop 2: agg(t2) -> Nb; GEMM -> out (deg<=5 rows)
    k_agg_tail4<<<AGG_BLOCKS, 256, 0, stream>>>(tB, Nb, inv0, rowptr, degi, col);
    k_gemm_tail<<<GEMM_BLOCKS, 128, 0, stream>>>(tB, Nb, tB, xb, tA, out, R + 256, Wp + 131072, inv2, degi, 1);
}